// Round 2
// baseline (1251.939 us; speedup 1.0000x reference)
//
#include <hip/hip_runtime.h>

#define N_NODES 50000
#define N_EDGES 800000
#define N_GRAPHS 64
#define LN_EPS 1e-5f

// ---------------------------------------------------------------------------
// Workspace layout (floats), ~51.9 MB total:
//   deg_in   : NPAD (int)     deg_out : NPAD (int)
//   dinv_in  : NPAD           dinv_out: NPAD
//   Hin      : N_NODES*64     (act @ W_in)   -- ALSO aliased as `act`
//   Hout     : N_NODES*64     (act @ W_out)
//   AccIn    : N_NODES*64     (aggregation target, seeded w/ self-loop term)
//   AccOut   : N_NODES*64
//   pool_sum : 64*64          cnt : 64 (int)
// act==Hin aliasing is safe: gemm blocks stage their own 64 rows of A to LDS
// (behind __syncthreads) before writing those same rows; rows are disjoint
// across blocks; combine writes Hin only after edge_kernel finished reading it.
// ---------------------------------------------------------------------------

__global__ __launch_bounds__(256) void init_kernel(int* deg_in, int* deg_out,
                                                   float* pool_sum, int* cnt) {
    int i = blockIdx.x * 256 + threadIdx.x;
    if (i < N_NODES) { deg_in[i] = 1; deg_out[i] = 1; }  // self-loop
    if (i < N_GRAPHS * 64) pool_sum[i] = 0.f;
    if (i < N_GRAPHS) cnt[i] = 0;
}

__global__ __launch_bounds__(256) void degree_kernel(const int* __restrict__ src,
                                                     const int* __restrict__ dst,
                                                     int* deg_in, int* deg_out) {
    int e = blockIdx.x * 256 + threadIdx.x;
    if (e >= N_EDGES) return;
    atomicAdd(&deg_in[dst[e]], 1);   // in-degree (conv_in normalization)
    atomicAdd(&deg_out[src[e]], 1);  // out-degree (conv_out normalization)
}

__global__ __launch_bounds__(256) void rsqrt_kernel(const int* __restrict__ deg_in,
                                                    const int* __restrict__ deg_out,
                                                    float* __restrict__ dinv_in,
                                                    float* __restrict__ dinv_out) {
    int i = blockIdx.x * 256 + threadIdx.x;
    if (i >= N_NODES) return;
    dinv_in[i]  = rsqrtf((float)deg_in[i]);   // deg >= 1 always (self-loops)
    dinv_out[i] = rsqrtf((float)deg_out[i]);
}

// Dual GEMM: Hin = A@Win, Hout = A@Wout; epilogue seeds Acc with the
// self-loop message h[i]*dinv[i]^2 (so edge kernel handles only real edges).
__global__ __launch_bounds__(256) void gemm_dual_kernel(
    const float* __restrict__ A,
    const float* __restrict__ Win, const float* __restrict__ Wout,
    const float* __restrict__ dinv_in, const float* __restrict__ dinv_out,
    float* __restrict__ Hin, float* __restrict__ Hout,
    float* __restrict__ AccIn, float* __restrict__ AccOut, int n) {
    __shared__ float sWin[64 * 64];
    __shared__ float sWout[64 * 64];
    __shared__ float sA[64 * 68];  // +4 pad keeps b128 aliasing at 2-way (free)
    const int tx = threadIdx.x;
    for (int i = tx * 4; i < 4096; i += 1024) {
        *(float4*)&sWin[i]  = *(const float4*)&Win[i];
        *(float4*)&sWout[i] = *(const float4*)&Wout[i];
    }
    const int row0 = blockIdx.x * 64;
    for (int i = tx; i < 1024; i += 256) {
        int r = i >> 4;
        int k4 = (i & 15) << 2;
        int gr = row0 + r;
        float4 v = make_float4(0.f, 0.f, 0.f, 0.f);
        if (gr < n) v = *(const float4*)&A[gr * 64 + k4];
        *(float4*)&sA[r * 68 + k4] = v;
    }
    __syncthreads();
    const int ct = tx & 15;   // col-thread: owns cols [ct*4, ct*4+4)
    const int rg = tx >> 4;   // row-group:  owns rows [rg*4, rg*4+4)
    const int c4 = ct << 2;
    float aI[4][4], aO[4][4];
#pragma unroll
    for (int i = 0; i < 4; ++i)
#pragma unroll
        for (int j = 0; j < 4; ++j) { aI[i][j] = 0.f; aO[i][j] = 0.f; }
#pragma unroll 4
    for (int k0 = 0; k0 < 64; k0 += 4) {
        float4 av[4];
#pragma unroll
        for (int i = 0; i < 4; ++i) av[i] = *(float4*)&sA[(rg * 4 + i) * 68 + k0];
#pragma unroll
        for (int kk = 0; kk < 4; ++kk) {
            float4 wi = *(float4*)&sWin[(k0 + kk) * 64 + c4];
            float4 wo = *(float4*)&sWout[(k0 + kk) * 64 + c4];
#pragma unroll
            for (int i = 0; i < 4; ++i) {
                float a = (&av[i].x)[kk];  // kk is compile-time (unrolled)
                aI[i][0] += a * wi.x; aI[i][1] += a * wi.y;
                aI[i][2] += a * wi.z; aI[i][3] += a * wi.w;
                aO[i][0] += a * wo.x; aO[i][1] += a * wo.y;
                aO[i][2] += a * wo.z; aO[i][3] += a * wo.w;
            }
        }
    }
#pragma unroll
    for (int i = 0; i < 4; ++i) {
        int gr = row0 + rg * 4 + i;
        if (gr < n) {
            float di = dinv_in[gr];  di *= di;
            float dq = dinv_out[gr]; dq *= dq;
            float4 vi = make_float4(aI[i][0], aI[i][1], aI[i][2], aI[i][3]);
            float4 vo = make_float4(aO[i][0], aO[i][1], aO[i][2], aO[i][3]);
            *(float4*)&Hin[gr * 64 + c4]  = vi;
            *(float4*)&Hout[gr * 64 + c4] = vo;
            float4 si = make_float4(vi.x * di, vi.y * di, vi.z * di, vi.w * di);
            float4 so = make_float4(vo.x * dq, vo.y * dq, vo.z * dq, vo.w * dq);
            *(float4*)&AccIn[gr * 64 + c4]  = si;
            *(float4*)&AccOut[gr * 64 + c4] = so;
        }
    }
}

// One wave per edge, lane = feature. Coalesced 256B gather + 256B atomic per
// direction. Edge metadata loads are wave-uniform (readfirstlane -> s_load).
__global__ __launch_bounds__(256) void edge_kernel(
    const int* __restrict__ src, const int* __restrict__ dst,
    const float* __restrict__ dinv_in, const float* __restrict__ dinv_out,
    const float* __restrict__ Hin, const float* __restrict__ Hout,
    float* __restrict__ AccIn, float* __restrict__ AccOut) {
    int e = (blockIdx.x << 2) + (threadIdx.x >> 6);
    if (e >= N_EDGES) return;
    e = __builtin_amdgcn_readfirstlane(e);
    const int lane = threadIdx.x & 63;
    const int s = src[e], d = dst[e];
    const float nin  = dinv_in[s] * dinv_in[d];
    const float nout = dinv_out[s] * dinv_out[d];
    float vi = Hin[s * 64 + lane];
    float vo = Hout[d * 64 + lane];
    unsafeAtomicAdd(&AccIn[d * 64 + lane], vi * nin);    // conv_in: s -> d
    unsafeAtomicAdd(&AccOut[s * 64 + lane], vo * nout);  // conv_out: d -> s
}

__global__ __launch_bounds__(256) void combine_kernel(
    const float* __restrict__ AccIn, const float* __restrict__ AccOut,
    const float* __restrict__ b_in, const float* __restrict__ b_out,
    float* __restrict__ out, int do_relu) {
    int idx = blockIdx.x * 256 + threadIdx.x;  // one float4 per thread
    if (idx >= N_NODES * 16) return;
    int f4 = (idx & 15) << 2;
    float4 ai = *(const float4*)&AccIn[idx << 2];
    float4 ao = *(const float4*)&AccOut[idx << 2];
    float4 bi = *(const float4*)&b_in[f4];
    float4 bo = *(const float4*)&b_out[f4];
    float4 r;
    r.x = 0.5f * (ao.x + bo.x) + 0.5f * (ai.x + bi.x);
    r.y = 0.5f * (ao.y + bo.y) + 0.5f * (ai.y + bi.y);
    r.z = 0.5f * (ao.z + bo.z) + 0.5f * (ai.z + bi.z);
    r.w = 0.5f * (ao.w + bo.w) + 0.5f * (ai.w + bi.w);
    if (do_relu) {
        r.x = fmaxf(r.x, 0.f); r.y = fmaxf(r.y, 0.f);
        r.z = fmaxf(r.z, 0.f); r.w = fmaxf(r.w, 0.f);
    }
    *(float4*)&out[idx << 2] = r;
}

// batch is sorted: run-length accumulate per wave (32 nodes), flush one
// atomic per (run, feature) instead of 3.2M scattered atomics.
__global__ __launch_bounds__(256) void pool_kernel(
    const float* __restrict__ h, const int* __restrict__ batch,
    float* __restrict__ pool_sum, int* __restrict__ cnt) {
    int w = (blockIdx.x << 2) + (threadIdx.x >> 6);
    int n0 = w << 5;
    if (n0 >= N_NODES) return;
    const int lane = threadIdx.x & 63;
    int n1 = min(n0 + 32, N_NODES);
    int g = batch[n0];
    float acc = 0.f;
    int run = 0;
    for (int nn = n0; nn < n1; ++nn) {
        int bg = batch[nn];
        if (bg != g) {
            unsafeAtomicAdd(&pool_sum[g * 64 + lane], acc);
            if (lane == 0) atomicAdd(&cnt[g], run);
            acc = 0.f; run = 0; g = bg;
        }
        acc += h[nn * 64 + lane];
        run++;
    }
    unsafeAtomicAdd(&pool_sum[g * 64 + lane], acc);
    if (lane == 0) atomicAdd(&cnt[g], run);
}

// One block (one wave, 64 threads) per graph: mean, LN, P1+relu, P2.
__global__ __launch_bounds__(64) void head_kernel(
    const float* __restrict__ pool_sum, const int* __restrict__ cnt,
    const float* __restrict__ ln_w, const float* __restrict__ ln_b,
    const float* __restrict__ P1w, const float* __restrict__ P1b,
    const float* __restrict__ P2w, const float* __restrict__ P2b,
    float* __restrict__ out) {
    __shared__ float zbuf[64];
    const int g = blockIdx.x, f = threadIdx.x;
    float c = fmaxf((float)cnt[g], 1.0f);
    float p = pool_sum[g * 64 + f] / c;
    float s = p;
#pragma unroll
    for (int o = 32; o >= 1; o >>= 1) s += __shfl_xor(s, o);
    float mu = s * (1.0f / 64.0f);
    float dv = p - mu;
    float q = dv * dv;
#pragma unroll
    for (int o = 32; o >= 1; o >>= 1) q += __shfl_xor(q, o);
    float var = q * (1.0f / 64.0f);
    float z = dv * rsqrtf(var + LN_EPS) * ln_w[f] + ln_b[f];
    zbuf[f] = z;
    __syncthreads();
    float s0 = 0.f, s1 = 0.f;
#pragma unroll 8
    for (int k = 0; k < 64; ++k) {
        float zk = zbuf[k];
        s0 += zk * P1w[k * 128 + f];
        s1 += zk * P1w[k * 128 + f + 64];
    }
    float r0 = fmaxf(s0 + P1b[f], 0.f);
    float r1 = fmaxf(s1 + P1b[f + 64], 0.f);
    float p0 = r0 * P2w[f * 2 + 0] + r1 * P2w[(f + 64) * 2 + 0];
    float p1 = r0 * P2w[f * 2 + 1] + r1 * P2w[(f + 64) * 2 + 1];
#pragma unroll
    for (int o = 32; o >= 1; o >>= 1) {
        p0 += __shfl_xor(p0, o);
        p1 += __shfl_xor(p1, o);
    }
    if (f == 0) {
        out[g * 2 + 0] = p0 + P2b[0];
        out[g * 2 + 1] = p1 + P2b[1];
    }
}

extern "C" void kernel_launch(void* const* d_in, const int* in_sizes, int n_in,
                              void* d_out, int out_size, void* d_ws, size_t ws_size,
                              hipStream_t stream) {
    const float* x     = (const float*)d_in[0];
    const int* esrc    = (const int*)d_in[1];
    const int* edst    = (const int*)d_in[2];
    const int* batch   = (const int*)d_in[3];
    const float* W1_in  = (const float*)d_in[4];
    const float* b1_in  = (const float*)d_in[5];
    const float* W1_out = (const float*)d_in[6];
    const float* b1_out = (const float*)d_in[7];
    const float* W2_in  = (const float*)d_in[8];
    const float* b2_in  = (const float*)d_in[9];
    const float* W2_out = (const float*)d_in[10];
    const float* b2_out = (const float*)d_in[11];
    const float* W3_in  = (const float*)d_in[12];
    const float* b3_in  = (const float*)d_in[13];
    const float* W3_out = (const float*)d_in[14];
    const float* b3_out = (const float*)d_in[15];
    const float* ln_w  = (const float*)d_in[16];
    const float* ln_b  = (const float*)d_in[17];
    const float* P1w   = (const float*)d_in[18];
    const float* P1b   = (const float*)d_in[19];
    const float* P2w   = (const float*)d_in[20];
    const float* P2b   = (const float*)d_in[21];
    float* out = (float*)d_out;

    float* ws = (float*)d_ws;
    const size_t NPAD = 50176;
    const size_t NF = (size_t)N_NODES * 64;
    int*   deg_in   = (int*)ws;
    int*   deg_out  = (int*)(ws + NPAD);
    float* dinv_in  = ws + 2 * NPAD;
    float* dinv_out = ws + 3 * NPAD;
    float* Hin      = ws + 4 * NPAD;
    float* Hout     = Hin + NF;
    float* AccIn    = Hout + NF;
    float* AccOut   = AccIn + NF;
    float* act      = Hin;               // aliased (safe; see header comment)
    float* pool_sum = AccOut + NF;
    int* cnt        = (int*)(pool_sum + N_GRAPHS * 64);

    const int nblk = (N_NODES + 255) / 256;
    init_kernel<<<nblk, 256, 0, stream>>>(deg_in, deg_out, pool_sum, cnt);
    degree_kernel<<<(N_EDGES + 255) / 256, 256, 0, stream>>>(esrc, edst, deg_in, deg_out);
    rsqrt_kernel<<<nblk, 256, 0, stream>>>(deg_in, deg_out, dinv_in, dinv_out);

    const int gemm_grid = (N_NODES + 63) / 64;
    const int edge_grid = (N_EDGES + 3) / 4;
    const int comb_grid = (N_NODES * 16 + 255) / 256;

    // layer 1
    gemm_dual_kernel<<<gemm_grid, 256, 0, stream>>>(x, W1_in, W1_out, dinv_in, dinv_out,
                                                    Hin, Hout, AccIn, AccOut, N_NODES);
    edge_kernel<<<edge_grid, 256, 0, stream>>>(esrc, edst, dinv_in, dinv_out, Hin, Hout, AccIn, AccOut);
    combine_kernel<<<comb_grid, 256, 0, stream>>>(AccIn, AccOut, b1_in, b1_out, act, 1);
    // layer 2
    gemm_dual_kernel<<<gemm_grid, 256, 0, stream>>>(act, W2_in, W2_out, dinv_in, dinv_out,
                                                    Hin, Hout, AccIn, AccOut, N_NODES);
    edge_kernel<<<edge_grid, 256, 0, stream>>>(esrc, edst, dinv_in, dinv_out, Hin, Hout, AccIn, AccOut);
    combine_kernel<<<comb_grid, 256, 0, stream>>>(AccIn, AccOut, b2_in, b2_out, act, 1);
    // layer 3
    gemm_dual_kernel<<<gemm_grid, 256, 0, stream>>>(act, W3_in, W3_out, dinv_in, dinv_out,
                                                    Hin, Hout, AccIn, AccOut, N_NODES);
    edge_kernel<<<edge_grid, 256, 0, stream>>>(esrc, edst, dinv_in, dinv_out, Hin, Hout, AccIn, AccOut);
    combine_kernel<<<comb_grid, 256, 0, stream>>>(AccIn, AccOut, b3_in, b3_out, act, 0);

    // pool + head
    pool_kernel<<<(N_NODES + 127) / 128, 256, 0, stream>>>(act, batch, pool_sum, cnt);
    head_kernel<<<N_GRAPHS, 64, 0, stream>>>(pool_sum, cnt, ln_w, ln_b, P1w, P1b, P2w, P2b, out);
}

// Round 4
// 585.794 us; speedup vs baseline: 2.1372x; 2.1372x over previous
//
#include <hip/hip_runtime.h>

#define N_NODES 50000
#define N_EDGES 800000
#define N_GRAPHS 64
#define LN_EPS 1e-5f
#define NPAD 50176

// ---------------------------------------------------------------------------
// Strategy: GCN aggregation commutes with the weight matrix:
//   (D^-1/2 (A+I) D^-1/2 x) @ W  ==  D^-1/2 (A+I) D^-1/2 (x @ W)
// So per layer: aggregate FIRST (node-parallel, no atomics, gathers from ONE
// hot 12.8MB array), then dual GEMM with fused bias + alpha-combine + relu.
//
// Workspace (floats, ~46.6 MB):
//   [0]       deg_in  (int)     [N]   deg_out (int)
//   [2N]      dinv_in           [3N]  dinv_out
//   [4N]      base_in (int)     [5N]  base_out (int)
//   [6N]      cur_in  (int)     [7N]  cur_out  (int)
//   [8N]      gc[2] (int) | pool_sum[4096] | cnt[64]
//   [9N]      act    (50000*64)
//   +NF       AggIn  (50000*64)
//   +2NF      AggOut (50000*64)
//   +3NF      csr_in (int, 800000) ; csr_out (int, 800000)
// ---------------------------------------------------------------------------

__global__ __launch_bounds__(256) void init_kernel(int* deg_in, int* deg_out,
                                                   int* gc, float* pool_sum, int* cnt) {
    int i = blockIdx.x * 256 + threadIdx.x;
    if (i < N_NODES) { deg_in[i] = 1; deg_out[i] = 1; }  // self-loop
    if (i < 2) gc[i] = 0;
    if (i < N_GRAPHS * 64) pool_sum[i] = 0.f;
    if (i < N_GRAPHS) cnt[i] = 0;
}

__global__ __launch_bounds__(256) void degree_kernel(const int* __restrict__ src,
                                                     const int* __restrict__ dst,
                                                     int* deg_in, int* deg_out) {
    int e = blockIdx.x * 256 + threadIdx.x;
    if (e >= N_EDGES) return;
    atomicAdd(&deg_in[dst[e]], 1);   // in-degree (conv_in side)
    atomicAdd(&deg_out[src[e]], 1);  // out-degree (conv_out side)
}

// dinv = rsqrt(deg); disjoint per-node CSR segments via block scan of real
// degrees + ONE atomicAdd per block per direction (order irrelevant).
__global__ __launch_bounds__(256) void prep_kernel(
    const int* __restrict__ deg_in, const int* __restrict__ deg_out,
    float* __restrict__ dinv_in, float* __restrict__ dinv_out,
    int* __restrict__ base_in, int* __restrict__ base_out,
    int* __restrict__ cur_in, int* __restrict__ cur_out, int* gc) {
    __shared__ int lws[4];
    const int i = blockIdx.x * 256 + threadIdx.x;
    const int tid = threadIdx.x, lane = tid & 63, wid = tid >> 6;

#pragma unroll
    for (int dir = 0; dir < 2; ++dir) {
        const int* deg = dir ? deg_out : deg_in;
        float* dinv    = dir ? dinv_out : dinv_in;
        int* base      = dir ? base_out : base_in;
        int* cur       = dir ? cur_out : cur_in;
        int d = (i < N_NODES) ? deg[i] : 1;
        if (i < N_NODES) dinv[i] = rsqrtf((float)d);
        int v = d - 1;            // real (non-self) degree
        int s = v;                // inclusive wave scan
#pragma unroll
        for (int off = 1; off < 64; off <<= 1) {
            int t = __shfl_up(s, off);
            if (lane >= off) s += t;
        }
        if (lane == 63) lws[wid] = s;
        __syncthreads();
        if (tid == 0) {
            int tmp[4]; int tot = 0;
            for (int w = 0; w < 4; ++w) { tmp[w] = tot; tot += lws[w]; }
            int bb = atomicAdd(&gc[dir], tot);
            for (int w = 0; w < 4; ++w) lws[w] = bb + tmp[w];
        }
        __syncthreads();
        int b = lws[wid] + s - v;  // exclusive position
        if (i < N_NODES) { base[i] = b; cur[i] = b; }
        __syncthreads();           // lws reused next dir
    }
}

__global__ __launch_bounds__(256) void scatter_kernel(
    const int* __restrict__ src, const int* __restrict__ dst,
    int* cur_in, int* cur_out, int* __restrict__ csr_in, int* __restrict__ csr_out) {
    int e = blockIdx.x * 256 + threadIdx.x;
    if (e >= N_EDGES) return;
    int s = src[e], d = dst[e];
    int p = atomicAdd(&cur_in[d], 1);
    csr_in[p] = s;                 // in-neighbors of d
    int q = atomicAdd(&cur_out[s], 1);
    csr_out[q] = d;                // out-neighbors of s
}

// One wave per node, lane = feature. Register accumulate over both neighbor
// lists; gathers are coalesced 256B rows from the single hot `act` array.
__global__ __launch_bounds__(256) void aggregate_kernel(
    const float* __restrict__ act,
    const int* __restrict__ deg_in, const int* __restrict__ deg_out,
    const float* __restrict__ dinv_in, const float* __restrict__ dinv_out,
    const int* __restrict__ base_in, const int* __restrict__ base_out,
    const int* __restrict__ csr_in, const int* __restrict__ csr_out,
    float* __restrict__ AggIn, float* __restrict__ AggOut) {
    int node = (blockIdx.x << 2) + (threadIdx.x >> 6);
    if (node >= N_NODES) return;
    const int lane = threadIdx.x & 63;
    const float di = dinv_in[node];
    const float dq = dinv_out[node];
    const float self = act[(size_t)node * 64 + lane];
    float aI = self * di * di;   // self-loop terms
    float aO = self * dq * dq;
    {
        const int b = base_in[node];
        const int n = deg_in[node] - 1;
        int j = 0;
        for (; j + 4 <= n; j += 4) {   // 4 independent gathers in flight
            int s0 = __builtin_amdgcn_readfirstlane(csr_in[b + j]);
            int s1 = __builtin_amdgcn_readfirstlane(csr_in[b + j + 1]);
            int s2 = __builtin_amdgcn_readfirstlane(csr_in[b + j + 2]);
            int s3 = __builtin_amdgcn_readfirstlane(csr_in[b + j + 3]);
            float w0 = dinv_in[s0], w1 = dinv_in[s1];
            float w2 = dinv_in[s2], w3 = dinv_in[s3];
            float v0 = act[(size_t)s0 * 64 + lane];
            float v1 = act[(size_t)s1 * 64 + lane];
            float v2 = act[(size_t)s2 * 64 + lane];
            float v3 = act[(size_t)s3 * 64 + lane];
            aI += di * (w0 * v0 + w1 * v1 + w2 * v2 + w3 * v3);
        }
        for (; j < n; ++j) {
            int s0 = __builtin_amdgcn_readfirstlane(csr_in[b + j]);
            aI += di * dinv_in[s0] * act[(size_t)s0 * 64 + lane];
        }
    }
    {
        const int b = base_out[node];
        const int n = deg_out[node] - 1;
        int j = 0;
        for (; j + 4 <= n; j += 4) {
            int s0 = __builtin_amdgcn_readfirstlane(csr_out[b + j]);
            int s1 = __builtin_amdgcn_readfirstlane(csr_out[b + j + 1]);
            int s2 = __builtin_amdgcn_readfirstlane(csr_out[b + j + 2]);
            int s3 = __builtin_amdgcn_readfirstlane(csr_out[b + j + 3]);
            float w0 = dinv_out[s0], w1 = dinv_out[s1];
            float w2 = dinv_out[s2], w3 = dinv_out[s3];
            float v0 = act[(size_t)s0 * 64 + lane];
            float v1 = act[(size_t)s1 * 64 + lane];
            float v2 = act[(size_t)s2 * 64 + lane];
            float v3 = act[(size_t)s3 * 64 + lane];
            aO += dq * (w0 * v0 + w1 * v1 + w2 * v2 + w3 * v3);
        }
        for (; j < n; ++j) {
            int s0 = __builtin_amdgcn_readfirstlane(csr_out[b + j]);
            aO += dq * dinv_out[s0] * act[(size_t)s0 * 64 + lane];
        }
    }
    AggIn[(size_t)node * 64 + lane]  = aI;
    AggOut[(size_t)node * 64 + lane] = aO;
}

// act_next = relu?(0.5*(AggOut@Wout + b_out) + 0.5*(AggIn@Win + b_in))
__global__ __launch_bounds__(256) void gemm_combine_kernel(
    const float* __restrict__ Ain, const float* __restrict__ Aout,
    const float* __restrict__ Win, const float* __restrict__ Wout,
    const float* __restrict__ b_in, const float* __restrict__ b_out,
    float* __restrict__ act, int do_relu) {
    __shared__ __align__(16) float sWin[64 * 64];
    __shared__ __align__(16) float sWout[64 * 64];
    __shared__ __align__(16) float sAin[64 * 68];   // +4 pad: 2-way max aliasing
    __shared__ __align__(16) float sAout[64 * 68];
    const int tx = threadIdx.x;
    for (int i = tx * 4; i < 4096; i += 1024) {
        *(float4*)&sWin[i]  = *(const float4*)&Win[i];
        *(float4*)&sWout[i] = *(const float4*)&Wout[i];
    }
    const int row0 = blockIdx.x * 64;
    for (int i = tx; i < 1024; i += 256) {
        int r = i >> 4;
        int k4 = (i & 15) << 2;
        int gr = row0 + r;
        float4 vi = make_float4(0.f, 0.f, 0.f, 0.f);
        float4 vo = vi;
        if (gr < N_NODES) {
            vi = *(const float4*)&Ain[(size_t)gr * 64 + k4];
            vo = *(const float4*)&Aout[(size_t)gr * 64 + k4];
        }
        *(float4*)&sAin[r * 68 + k4]  = vi;
        *(float4*)&sAout[r * 68 + k4] = vo;
    }
    __syncthreads();
    const int ct = tx & 15;   // cols [ct*4, ct*4+4)
    const int rg = tx >> 4;   // rows [rg*4, rg*4+4)
    const int c4 = ct << 2;
    float aI[4][4], aO[4][4];
#pragma unroll
    for (int i = 0; i < 4; ++i)
#pragma unroll
        for (int j = 0; j < 4; ++j) { aI[i][j] = 0.f; aO[i][j] = 0.f; }
#pragma unroll 4
    for (int k0 = 0; k0 < 64; k0 += 4) {
        float4 avI[4], avO[4];
#pragma unroll
        for (int i = 0; i < 4; ++i) {
            avI[i] = *(float4*)&sAin[(rg * 4 + i) * 68 + k0];
            avO[i] = *(float4*)&sAout[(rg * 4 + i) * 68 + k0];
        }
#pragma unroll
        for (int kk = 0; kk < 4; ++kk) {
            float4 wi = *(float4*)&sWin[(k0 + kk) * 64 + c4];
            float4 wo = *(float4*)&sWout[(k0 + kk) * 64 + c4];
#pragma unroll
            for (int i = 0; i < 4; ++i) {
                float ai = (&avI[i].x)[kk];
                float ao = (&avO[i].x)[kk];
                aI[i][0] += ai * wi.x; aI[i][1] += ai * wi.y;
                aI[i][2] += ai * wi.z; aI[i][3] += ai * wi.w;
                aO[i][0] += ao * wo.x; aO[i][1] += ao * wo.y;
                aO[i][2] += ao * wo.z; aO[i][3] += ao * wo.w;
            }
        }
    }
    float4 bi = *(const float4*)&b_in[c4];
    float4 bo = *(const float4*)&b_out[c4];
#pragma unroll
    for (int i = 0; i < 4; ++i) {
        int gr = row0 + rg * 4 + i;
        if (gr < N_NODES) {
            float4 r;
            r.x = 0.5f * (aO[i][0] + bo.x) + 0.5f * (aI[i][0] + bi.x);
            r.y = 0.5f * (aO[i][1] + bo.y) + 0.5f * (aI[i][1] + bi.y);
            r.z = 0.5f * (aO[i][2] + bo.z) + 0.5f * (aI[i][2] + bi.z);
            r.w = 0.5f * (aO[i][3] + bo.w) + 0.5f * (aI[i][3] + bi.w);
            if (do_relu) {
                r.x = fmaxf(r.x, 0.f); r.y = fmaxf(r.y, 0.f);
                r.z = fmaxf(r.z, 0.f); r.w = fmaxf(r.w, 0.f);
            }
            *(float4*)&act[(size_t)gr * 64 + c4] = r;
        }
    }
}

// batch is sorted: run-length accumulate per wave (32 nodes), flush one
// atomic per (run, feature).
__global__ __launch_bounds__(256) void pool_kernel(
    const float* __restrict__ h, const int* __restrict__ batch,
    float* __restrict__ pool_sum, int* __restrict__ cnt) {
    int w = (blockIdx.x << 2) + (threadIdx.x >> 6);
    int n0 = w << 5;
    if (n0 >= N_NODES) return;
    const int lane = threadIdx.x & 63;
    int n1 = min(n0 + 32, N_NODES);
    int g = batch[n0];
    float acc = 0.f;
    int run = 0;
    for (int nn = n0; nn < n1; ++nn) {
        int bg = batch[nn];
        if (bg != g) {
            unsafeAtomicAdd(&pool_sum[g * 64 + lane], acc);
            if (lane == 0) atomicAdd(&cnt[g], run);
            acc = 0.f; run = 0; g = bg;
        }
        acc += h[(size_t)nn * 64 + lane];
        run++;
    }
    unsafeAtomicAdd(&pool_sum[g * 64 + lane], acc);
    if (lane == 0) atomicAdd(&cnt[g], run);
}

// One wave per graph: mean, LN, P1+relu, P2.
__global__ __launch_bounds__(64) void head_kernel(
    const float* __restrict__ pool_sum, const int* __restrict__ cnt,
    const float* __restrict__ ln_w, const float* __restrict__ ln_b,
    const float* __restrict__ P1w, const float* __restrict__ P1b,
    const float* __restrict__ P2w, const float* __restrict__ P2b,
    float* __restrict__ out) {
    __shared__ float zbuf[64];
    const int g = blockIdx.x, f = threadIdx.x;
    float c = fmaxf((float)cnt[g], 1.0f);
    float p = pool_sum[g * 64 + f] / c;
    float s = p;
#pragma unroll
    for (int o = 32; o >= 1; o >>= 1) s += __shfl_xor(s, o);
    float mu = s * (1.0f / 64.0f);
    float dv = p - mu;
    float q = dv * dv;
#pragma unroll
    for (int o = 32; o >= 1; o >>= 1) q += __shfl_xor(q, o);
    float var = q * (1.0f / 64.0f);
    float z = dv * rsqrtf(var + LN_EPS) * ln_w[f] + ln_b[f];
    zbuf[f] = z;
    __syncthreads();
    float s0 = 0.f, s1 = 0.f;
#pragma unroll 8
    for (int k = 0; k < 64; ++k) {
        float zk = zbuf[k];
        s0 += zk * P1w[k * 128 + f];
        s1 += zk * P1w[k * 128 + f + 64];
    }
    float r0 = fmaxf(s0 + P1b[f], 0.f);
    float r1 = fmaxf(s1 + P1b[f + 64], 0.f);
    float p0 = r0 * P2w[f * 2 + 0] + r1 * P2w[(f + 64) * 2 + 0];
    float p1 = r0 * P2w[f * 2 + 1] + r1 * P2w[(f + 64) * 2 + 1];
#pragma unroll
    for (int o = 32; o >= 1; o >>= 1) {
        p0 += __shfl_xor(p0, o);
        p1 += __shfl_xor(p1, o);
    }
    if (f == 0) {
        out[g * 2 + 0] = p0 + P2b[0];
        out[g * 2 + 1] = p1 + P2b[1];
    }
}

extern "C" void kernel_launch(void* const* d_in, const int* in_sizes, int n_in,
                              void* d_out, int out_size, void* d_ws, size_t ws_size,
                              hipStream_t stream) {
    const float* x     = (const float*)d_in[0];
    const int* esrc    = (const int*)d_in[1];
    const int* edst    = (const int*)d_in[2];
    const int* batch   = (const int*)d_in[3];
    const float* W1_in  = (const float*)d_in[4];
    const float* b1_in  = (const float*)d_in[5];
    const float* W1_out = (const float*)d_in[6];
    const float* b1_out = (const float*)d_in[7];
    const float* W2_in  = (const float*)d_in[8];
    const float* b2_in  = (const float*)d_in[9];
    const float* W2_out = (const float*)d_in[10];
    const float* b2_out = (const float*)d_in[11];
    const float* W3_in  = (const float*)d_in[12];
    const float* b3_in  = (const float*)d_in[13];
    const float* W3_out = (const float*)d_in[14];
    const float* b3_out = (const float*)d_in[15];
    const float* ln_w  = (const float*)d_in[16];
    const float* ln_b  = (const float*)d_in[17];
    const float* P1w   = (const float*)d_in[18];
    const float* P1b   = (const float*)d_in[19];
    const float* P2w   = (const float*)d_in[20];
    const float* P2b   = (const float*)d_in[21];
    float* out = (float*)d_out;

    float* ws = (float*)d_ws;
    const size_t NF = (size_t)N_NODES * 64;
    int*   deg_in   = (int*)(ws + 0 * NPAD);
    int*   deg_out  = (int*)(ws + 1 * NPAD);
    float* dinv_in  = ws + 2 * NPAD;
    float* dinv_out = ws + 3 * NPAD;
    int*   base_in  = (int*)(ws + 4 * NPAD);
    int*   base_out = (int*)(ws + 5 * NPAD);
    int*   cur_in   = (int*)(ws + 6 * NPAD);
    int*   cur_out  = (int*)(ws + 7 * NPAD);
    int*   gc       = (int*)(ws + 8 * NPAD);
    float* pool_sum = ws + 8 * NPAD + 64;
    int*   cnt      = (int*)(ws + 8 * NPAD + 64 + 4096);
    float* act      = ws + 9 * NPAD;
    float* AggIn    = act + NF;
    float* AggOut   = AggIn + NF;
    int*   csr_in   = (int*)(AggOut + NF);
    int*   csr_out  = csr_in + N_EDGES;

    const int nblk = (N_NODES + 255) / 256;
    init_kernel<<<nblk, 256, 0, stream>>>(deg_in, deg_out, gc, pool_sum, cnt);
    degree_kernel<<<(N_EDGES + 255) / 256, 256, 0, stream>>>(esrc, edst, deg_in, deg_out);
    prep_kernel<<<nblk, 256, 0, stream>>>(deg_in, deg_out, dinv_in, dinv_out,
                                          base_in, base_out, cur_in, cur_out, gc);
    scatter_kernel<<<(N_EDGES + 255) / 256, 256, 0, stream>>>(esrc, edst, cur_in, cur_out,
                                                              csr_in, csr_out);

    const int agg_grid  = (N_NODES + 3) / 4;
    const int gemm_grid = (N_NODES + 63) / 64;

    // layer 1 (aggregate reads x directly)
    aggregate_kernel<<<agg_grid, 256, 0, stream>>>(x, deg_in, deg_out, dinv_in, dinv_out,
                                                   base_in, base_out, csr_in, csr_out,
                                                   AggIn, AggOut);
    gemm_combine_kernel<<<gemm_grid, 256, 0, stream>>>(AggIn, AggOut, W1_in, W1_out,
                                                       b1_in, b1_out, act, 1);
    // layer 2
    aggregate_kernel<<<agg_grid, 256, 0, stream>>>(act, deg_in, deg_out, dinv_in, dinv_out,
                                                   base_in, base_out, csr_in, csr_out,
                                                   AggIn, AggOut);
    gemm_combine_kernel<<<gemm_grid, 256, 0, stream>>>(AggIn, AggOut, W2_in, W2_out,
                                                       b2_in, b2_out, act, 1);
    // layer 3 (no relu)
    aggregate_kernel<<<agg_grid, 256, 0, stream>>>(act, deg_in, deg_out, dinv_in, dinv_out,
                                                   base_in, base_out, csr_in, csr_out,
                                                   AggIn, AggOut);
    gemm_combine_kernel<<<gemm_grid, 256, 0, stream>>>(AggIn, AggOut, W3_in, W3_out,
                                                       b3_in, b3_out, act, 0);

    // pool + head
    pool_kernel<<<(N_NODES + 127) / 128, 256, 0, stream>>>(act, batch, pool_sum, cnt);
    head_kernel<<<N_GRAPHS, 64, 0, stream>>>(pool_sum, cnt, ln_w, ln_b, P1w, P1b, P2w, P2b, out);
}

// Round 6
// 538.463 us; speedup vs baseline: 2.3250x; 1.0879x over previous
//
#include <hip/hip_runtime.h>

#define N_NODES 50000
#define N_EDGES 800000
#define N_GRAPHS 64
#define LN_EPS 1e-5f
#define NPAD 50176
#define NXCD 8
#define NODES_PER_GRP (N_NODES / NXCD)   // 6250
#define BPG 128                          // blocks per XCD-group for build passes

// ---------------------------------------------------------------------------
// Aggregate-first DirGNN. CSR build is XCD-partitioned: blocks with
// (blockIdx&7)==g own node range [g*6250,(g+1)*6250) and scan all edges,
// so degree atomics, slot atomics, and csr placement writes all stay in ONE
// XCD's L2 (fixes R4's 105MB partial-line writeback storm on scatter).
//
// Workspace (floats, ~46.6 MB): see offsets in kernel_launch.
// ---------------------------------------------------------------------------

__global__ __launch_bounds__(256) void init_kernel(int* deg_in, int* deg_out,
                                                   int* gc, float* pool_sum, int* cnt) {
    int i = blockIdx.x * 256 + threadIdx.x;
    if (i < N_NODES) { deg_in[i] = 1; deg_out[i] = 1; }  // self-loop
    if (i < 2) gc[i] = 0;
    if (i < N_GRAPHS * 64) pool_sum[i] = 0.f;
    if (i < N_GRAPHS) cnt[i] = 0;
}

// XCD-partitioned degree count: group g touches only deg slices in its range.
__global__ __launch_bounds__(256) void degree_kernel(const int* __restrict__ src,
                                                     const int* __restrict__ dst,
                                                     int* deg_in, int* deg_out) {
    const int g   = blockIdx.x & (NXCD - 1);
    const int sub = blockIdx.x >> 3;
    const int lo = g * NODES_PER_GRP, hi = lo + NODES_PER_GRP;
    for (int e = sub * 256 + threadIdx.x; e < N_EDGES; e += BPG * 256) {
        int s = src[e], d = dst[e];
        if (d >= lo && d < hi) atomicAdd(&deg_in[d], 1);   // in-degree
        if (s >= lo && s < hi) atomicAdd(&deg_out[s], 1);  // out-degree
    }
}

// dinv = rsqrt(deg); disjoint per-node CSR segments via block scan of real
// degrees + ONE atomicAdd per block per direction (order irrelevant).
__global__ __launch_bounds__(256) void prep_kernel(
    const int* __restrict__ deg_in, const int* __restrict__ deg_out,
    float* __restrict__ dinv_in, float* __restrict__ dinv_out,
    int* __restrict__ base_in, int* __restrict__ base_out,
    int* __restrict__ cur_in, int* __restrict__ cur_out, int* gc) {
    __shared__ int lws[4];
    const int i = blockIdx.x * 256 + threadIdx.x;
    const int tid = threadIdx.x, lane = tid & 63, wid = tid >> 6;

#pragma unroll
    for (int dir = 0; dir < 2; ++dir) {
        const int* deg = dir ? deg_out : deg_in;
        float* dinv    = dir ? dinv_out : dinv_in;
        int* base      = dir ? base_out : base_in;
        int* cur       = dir ? cur_out : cur_in;
        int d = (i < N_NODES) ? deg[i] : 1;
        if (i < N_NODES) dinv[i] = rsqrtf((float)d);
        int v = d - 1;            // real (non-self) degree
        int s = v;                // inclusive wave scan
#pragma unroll
        for (int off = 1; off < 64; off <<= 1) {
            int t = __shfl_up(s, off);
            if (lane >= off) s += t;
        }
        if (lane == 63) lws[wid] = s;
        __syncthreads();
        if (tid == 0) {
            int tmp[4]; int tot = 0;
            for (int w = 0; w < 4; ++w) { tmp[w] = tot; tot += lws[w]; }
            int bb = atomicAdd(&gc[dir], tot);
            for (int w = 0; w < 4; ++w) lws[w] = bb + tmp[w];
        }
        __syncthreads();
        int b = lws[wid] + s - v;  // exclusive position
        if (i < N_NODES) { base[i] = b; cur[i] = b; }
        __syncthreads();           // lws reused next dir
    }
}

// NOTE: base assignment is block-order dependent, but each node's segment is
// disjoint and aggregation sums whole segments -> result invariant.

// XCD-partitioned placement: group g claims slots + writes csr only for its
// node range; its cur slice (25KB) and csr output region (~400KB contiguous,
// since base is monotonic in node id) stay in one XCD's L2 -> merged lines.
__global__ __launch_bounds__(256) void place_kernel(
    const int* __restrict__ src, const int* __restrict__ dst,
    int* cur_in, int* cur_out, int* __restrict__ csr_in, int* __restrict__ csr_out) {
    const int g   = blockIdx.x & (NXCD - 1);
    const int sub = blockIdx.x >> 3;
    const int lo = g * NODES_PER_GRP, hi = lo + NODES_PER_GRP;
    for (int e = sub * 256 + threadIdx.x; e < N_EDGES; e += BPG * 256) {
        int s = src[e], d = dst[e];
        if (d >= lo && d < hi) {
            int p = atomicAdd(&cur_in[d], 1);
            csr_in[p] = s;                 // in-neighbors of d
        }
        if (s >= lo && s < hi) {
            int q = atomicAdd(&cur_out[s], 1);
            csr_out[q] = d;                // out-neighbors of s
        }
    }
}

// One wave per node, lane = feature. 8 independent gathers in flight;
// raw-sum accumulate, scale once at the end.
__global__ __launch_bounds__(256) void aggregate_kernel(
    const float* __restrict__ act,
    const int* __restrict__ deg_in, const int* __restrict__ deg_out,
    const float* __restrict__ dinv_in, const float* __restrict__ dinv_out,
    const int* __restrict__ base_in, const int* __restrict__ base_out,
    const int* __restrict__ csr_in, const int* __restrict__ csr_out,
    float* __restrict__ AggIn, float* __restrict__ AggOut) {
    int node = (blockIdx.x << 2) + (threadIdx.x >> 6);
    if (node >= N_NODES) return;
    const int lane = threadIdx.x & 63;
    const float di = dinv_in[node];
    const float dq = dinv_out[node];
    const float self = act[(size_t)node * 64 + lane];
    float sumI = 0.f, sumO = 0.f;
    {
        const int b = base_in[node];
        const int n = deg_in[node] - 1;
        int j = 0;
        for (; j + 8 <= n; j += 8) {
            int s0 = __builtin_amdgcn_readfirstlane(csr_in[b + j]);
            int s1 = __builtin_amdgcn_readfirstlane(csr_in[b + j + 1]);
            int s2 = __builtin_amdgcn_readfirstlane(csr_in[b + j + 2]);
            int s3 = __builtin_amdgcn_readfirstlane(csr_in[b + j + 3]);
            int s4 = __builtin_amdgcn_readfirstlane(csr_in[b + j + 4]);
            int s5 = __builtin_amdgcn_readfirstlane(csr_in[b + j + 5]);
            int s6 = __builtin_amdgcn_readfirstlane(csr_in[b + j + 6]);
            int s7 = __builtin_amdgcn_readfirstlane(csr_in[b + j + 7]);
            float w0 = dinv_in[s0], w1 = dinv_in[s1], w2 = dinv_in[s2], w3 = dinv_in[s3];
            float w4 = dinv_in[s4], w5 = dinv_in[s5], w6 = dinv_in[s6], w7 = dinv_in[s7];
            float v0 = act[(size_t)s0 * 64 + lane];
            float v1 = act[(size_t)s1 * 64 + lane];
            float v2 = act[(size_t)s2 * 64 + lane];
            float v3 = act[(size_t)s3 * 64 + lane];
            float v4 = act[(size_t)s4 * 64 + lane];
            float v5 = act[(size_t)s5 * 64 + lane];
            float v6 = act[(size_t)s6 * 64 + lane];
            float v7 = act[(size_t)s7 * 64 + lane];
            sumI += (w0 * v0 + w1 * v1 + w2 * v2 + w3 * v3)
                  + (w4 * v4 + w5 * v5 + w6 * v6 + w7 * v7);
        }
        for (; j < n; ++j) {
            int s0 = __builtin_amdgcn_readfirstlane(csr_in[b + j]);
            sumI += dinv_in[s0] * act[(size_t)s0 * 64 + lane];
        }
    }
    {
        const int b = base_out[node];
        const int n = deg_out[node] - 1;
        int j = 0;
        for (; j + 8 <= n; j += 8) {
            int s0 = __builtin_amdgcn_readfirstlane(csr_out[b + j]);
            int s1 = __builtin_amdgcn_readfirstlane(csr_out[b + j + 1]);
            int s2 = __builtin_amdgcn_readfirstlane(csr_out[b + j + 2]);
            int s3 = __builtin_amdgcn_readfirstlane(csr_out[b + j + 3]);
            int s4 = __builtin_amdgcn_readfirstlane(csr_out[b + j + 4]);
            int s5 = __builtin_amdgcn_readfirstlane(csr_out[b + j + 5]);
            int s6 = __builtin_amdgcn_readfirstlane(csr_out[b + j + 6]);
            int s7 = __builtin_amdgcn_readfirstlane(csr_out[b + j + 7]);
            float w0 = dinv_out[s0], w1 = dinv_out[s1], w2 = dinv_out[s2], w3 = dinv_out[s3];
            float w4 = dinv_out[s4], w5 = dinv_out[s5], w6 = dinv_out[s6], w7 = dinv_out[s7];
            float v0 = act[(size_t)s0 * 64 + lane];
            float v1 = act[(size_t)s1 * 64 + lane];
            float v2 = act[(size_t)s2 * 64 + lane];
            float v3 = act[(size_t)s3 * 64 + lane];
            float v4 = act[(size_t)s4 * 64 + lane];
            float v5 = act[(size_t)s5 * 64 + lane];
            float v6 = act[(size_t)s6 * 64 + lane];
            float v7 = act[(size_t)s7 * 64 + lane];
            sumO += (w0 * v0 + w1 * v1 + w2 * v2 + w3 * v3)
                  + (w4 * v4 + w5 * v5 + w6 * v6 + w7 * v7);
        }
        for (; j < n; ++j) {
            int s0 = __builtin_amdgcn_readfirstlane(csr_out[b + j]);
            sumO += dinv_out[s0] * act[(size_t)s0 * 64 + lane];
        }
    }
    AggIn[(size_t)node * 64 + lane]  = di * (di * self + sumI);
    AggOut[(size_t)node * 64 + lane] = dq * (dq * self + sumO);
}

// act_next = relu?(0.5*(AggOut@Wout + b_out) + 0.5*(AggIn@Win + b_in))
__global__ __launch_bounds__(256) void gemm_combine_kernel(
    const float* __restrict__ Ain, const float* __restrict__ Aout,
    const float* __restrict__ Win, const float* __restrict__ Wout,
    const float* __restrict__ b_in, const float* __restrict__ b_out,
    float* __restrict__ act, int do_relu) {
    __shared__ __align__(16) float sWin[64 * 64];
    __shared__ __align__(16) float sWout[64 * 64];
    __shared__ __align__(16) float sAin[64 * 68];   // +4 pad: 2-way max aliasing
    __shared__ __align__(16) float sAout[64 * 68];
    const int tx = threadIdx.x;
    for (int i = tx * 4; i < 4096; i += 1024) {
        *(float4*)&sWin[i]  = *(const float4*)&Win[i];
        *(float4*)&sWout[i] = *(const float4*)&Wout[i];
    }
    const int row0 = blockIdx.x * 64;
    for (int i = tx; i < 1024; i += 256) {
        int r = i >> 4;
        int k4 = (i & 15) << 2;
        int gr = row0 + r;
        float4 vi = make_float4(0.f, 0.f, 0.f, 0.f);
        float4 vo = vi;
        if (gr < N_NODES) {
            vi = *(const float4*)&Ain[(size_t)gr * 64 + k4];
            vo = *(const float4*)&Aout[(size_t)gr * 64 + k4];
        }
        *(float4*)&sAin[r * 68 + k4]  = vi;
        *(float4*)&sAout[r * 68 + k4] = vo;
    }
    __syncthreads();
    const int ct = tx & 15;   // cols [ct*4, ct*4+4)
    const int rg = tx >> 4;   // rows [rg*4, rg*4+4)
    const int c4 = ct << 2;
    float aI[4][4], aO[4][4];
#pragma unroll
    for (int i = 0; i < 4; ++i)
#pragma unroll
        for (int j = 0; j < 4; ++j) { aI[i][j] = 0.f; aO[i][j] = 0.f; }
#pragma unroll 4
    for (int k0 = 0; k0 < 64; k0 += 4) {
        float4 avI[4], avO[4];
#pragma unroll
        for (int i = 0; i < 4; ++i) {
            avI[i] = *(float4*)&sAin[(rg * 4 + i) * 68 + k0];
            avO[i] = *(float4*)&sAout[(rg * 4 + i) * 68 + k0];
        }
#pragma unroll
        for (int kk = 0; kk < 4; ++kk) {
            float4 wi = *(float4*)&sWin[(k0 + kk) * 64 + c4];
            float4 wo = *(float4*)&sWout[(k0 + kk) * 64 + c4];
#pragma unroll
            for (int i = 0; i < 4; ++i) {
                float ai = (&avI[i].x)[kk];
                float ao = (&avO[i].x)[kk];
                aI[i][0] += ai * wi.x; aI[i][1] += ai * wi.y;
                aI[i][2] += ai * wi.z; aI[i][3] += ai * wi.w;
                aO[i][0] += ao * wo.x; aO[i][1] += ao * wo.y;
                aO[i][2] += ao * wo.z; aO[i][3] += ao * wo.w;
            }
        }
    }
    float4 bi = *(const float4*)&b_in[c4];
    float4 bo = *(const float4*)&b_out[c4];
#pragma unroll
    for (int i = 0; i < 4; ++i) {
        int gr = row0 + rg * 4 + i;
        if (gr < N_NODES) {
            float4 r;
            r.x = 0.5f * (aO[i][0] + bo.x) + 0.5f * (aI[i][0] + bi.x);
            r.y = 0.5f * (aO[i][1] + bo.y) + 0.5f * (aI[i][1] + bi.y);
            r.z = 0.5f * (aO[i][2] + bo.z) + 0.5f * (aI[i][2] + bi.z);
            r.w = 0.5f * (aO[i][3] + bo.w) + 0.5f * (aI[i][3] + bi.w);
            if (do_relu) {
                r.x = fmaxf(r.x, 0.f); r.y = fmaxf(r.y, 0.f);
                r.z = fmaxf(r.z, 0.f); r.w = fmaxf(r.w, 0.f);
            }
            *(float4*)&act[(size_t)gr * 64 + c4] = r;
        }
    }
}

// batch is sorted: run-length accumulate per wave (32 nodes), flush one
// atomic per (run, feature).
__global__ __launch_bounds__(256) void pool_kernel(
    const float* __restrict__ h, const int* __restrict__ batch,
    float* __restrict__ pool_sum, int* __restrict__ cnt) {
    int w = (blockIdx.x << 2) + (threadIdx.x >> 6);
    int n0 = w << 5;
    if (n0 >= N_NODES) return;
    const int lane = threadIdx.x & 63;
    int n1 = min(n0 + 32, N_NODES);
    int g = batch[n0];
    float acc = 0.f;
    int run = 0;
    for (int nn = n0; nn < n1; ++nn) {
        int bg = batch[nn];
        if (bg != g) {
            unsafeAtomicAdd(&pool_sum[g * 64 + lane], acc);
            if (lane == 0) atomicAdd(&cnt[g], run);
            acc = 0.f; run = 0; g = bg;
        }
        acc += h[(size_t)nn * 64 + lane];
        run++;
    }
    unsafeAtomicAdd(&pool_sum[g * 64 + lane], acc);
    if (lane == 0) atomicAdd(&cnt[g], run);
}

// One wave per graph: mean, LN, P1+relu, P2.
__global__ __launch_bounds__(64) void head_kernel(
    const float* __restrict__ pool_sum, const int* __restrict__ cnt,
    const float* __restrict__ ln_w, const float* __restrict__ ln_b,
    const float* __restrict__ P1w, const float* __restrict__ P1b,
    const float* __restrict__ P2w, const float* __restrict__ P2b,
    float* __restrict__ out) {
    __shared__ float zbuf[64];
    const int g = blockIdx.x, f = threadIdx.x;
    float c = fmaxf((float)cnt[g], 1.0f);
    float p = pool_sum[g * 64 + f] / c;
    float s = p;
#pragma unroll
    for (int o = 32; o >= 1; o >>= 1) s += __shfl_xor(s, o);
    float mu = s * (1.0f / 64.0f);
    float dv = p - mu;
    float q = dv * dv;
#pragma unroll
    for (int o = 32; o >= 1; o >>= 1) q += __shfl_xor(q, o);
    float var = q * (1.0f / 64.0f);
    float z = dv * rsqrtf(var + LN_EPS) * ln_w[f] + ln_b[f];
    zbuf[f] = z;
    __syncthreads();
    float s0 = 0.f, s1 = 0.f;
#pragma unroll 8
    for (int k = 0; k < 64; ++k) {
        float zk = zbuf[k];
        s0 += zk * P1w[k * 128 + f];
        s1 += zk * P1w[k * 128 + f + 64];
    }
    float r0 = fmaxf(s0 + P1b[f], 0.f);
    float r1 = fmaxf(s1 + P1b[f + 64], 0.f);
    float p0 = r0 * P2w[f * 2 + 0] + r1 * P2w[(f + 64) * 2 + 0];
    float p1 = r0 * P2w[f * 2 + 1] + r1 * P2w[(f + 64) * 2 + 1];
#pragma unroll
    for (int o = 32; o >= 1; o >>= 1) {
        p0 += __shfl_xor(p0, o);
        p1 += __shfl_xor(p1, o);
    }
    if (f == 0) {
        out[g * 2 + 0] = p0 + P2b[0];
        out[g * 2 + 1] = p1 + P2b[1];
    }
}

extern "C" void kernel_launch(void* const* d_in, const int* in_sizes, int n_in,
                              void* d_out, int out_size, void* d_ws, size_t ws_size,
                              hipStream_t stream) {
    const float* x     = (const float*)d_in[0];
    const int* esrc    = (const int*)d_in[1];
    const int* edst    = (const int*)d_in[2];
    const int* batch   = (const int*)d_in[3];
    const float* W1_in  = (const float*)d_in[4];
    const float* b1_in  = (const float*)d_in[5];
    const float* W1_out = (const float*)d_in[6];
    const float* b1_out = (const float*)d_in[7];
    const float* W2_in  = (const float*)d_in[8];
    const float* b2_in  = (const float*)d_in[9];
    const float* W2_out = (const float*)d_in[10];
    const float* b2_out = (const float*)d_in[11];
    const float* W3_in  = (const float*)d_in[12];
    const float* b3_in  = (const float*)d_in[13];
    const float* W3_out = (const float*)d_in[14];
    const float* b3_out = (const float*)d_in[15];
    const float* ln_w  = (const float*)d_in[16];
    const float* ln_b  = (const float*)d_in[17];
    const float* P1w   = (const float*)d_in[18];
    const float* P1b   = (const float*)d_in[19];
    const float* P2w   = (const float*)d_in[20];
    const float* P2b   = (const float*)d_in[21];
    float* out = (float*)d_out;

    float* ws = (float*)d_ws;
    const size_t NF = (size_t)N_NODES * 64;
    int*   deg_in   = (int*)(ws + 0 * NPAD);
    int*   deg_out  = (int*)(ws + 1 * NPAD);
    float* dinv_in  = ws + 2 * NPAD;
    float* dinv_out = ws + 3 * NPAD;
    int*   base_in  = (int*)(ws + 4 * NPAD);
    int*   base_out = (int*)(ws + 5 * NPAD);
    int*   cur_in   = (int*)(ws + 6 * NPAD);
    int*   cur_out  = (int*)(ws + 7 * NPAD);
    int*   gc       = (int*)(ws + 8 * NPAD);
    float* pool_sum = ws + 8 * NPAD + 64;
    int*   cnt      = (int*)(ws + 8 * NPAD + 64 + 4096);
    float* act      = ws + 9 * NPAD;
    float* AggIn    = act + NF;
    float* AggOut   = AggIn + NF;
    int*   csr_in   = (int*)(AggOut + NF);
    int*   csr_out  = csr_in + N_EDGES;

    const int nblk = (N_NODES + 255) / 256;
    init_kernel<<<nblk, 256, 0, stream>>>(deg_in, deg_out, gc, pool_sum, cnt);
    degree_kernel<<<NXCD * BPG, 256, 0, stream>>>(esrc, edst, deg_in, deg_out);
    prep_kernel<<<nblk, 256, 0, stream>>>(deg_in, deg_out, dinv_in, dinv_out,
                                          base_in, base_out, cur_in, cur_out, gc);
    place_kernel<<<NXCD * BPG, 256, 0, stream>>>(esrc, edst, cur_in, cur_out,
                                                 csr_in, csr_out);

    const int agg_grid  = (N_NODES + 3) / 4;
    const int gemm_grid = (N_NODES + 63) / 64;

    // layer 1 (aggregate reads x directly)
    aggregate_kernel<<<agg_grid, 256, 0, stream>>>(x, deg_in, deg_out, dinv_in, dinv_out,
                                                   base_in, base_out, csr_in, csr_out,
                                                   AggIn, AggOut);
    gemm_combine_kernel<<<gemm_grid, 256, 0, stream>>>(AggIn, AggOut, W1_in, W1_out,
                                                       b1_in, b1_out, act, 1);
    // layer 2
    aggregate_kernel<<<agg_grid, 256, 0, stream>>>(act, deg_in, deg_out, dinv_in, dinv_out,
                                                   base_in, base_out, csr_in, csr_out,
                                                   AggIn, AggOut);
    gemm_combine_kernel<<<gemm_grid, 256, 0, stream>>>(AggIn, AggOut, W2_in, W2_out,
                                                       b2_in, b2_out, act, 1);
    // layer 3 (no relu)
    aggregate_kernel<<<agg_grid, 256, 0, stream>>>(act, deg_in, deg_out, dinv_in, dinv_out,
                                                   base_in, base_out, csr_in, csr_out,
                                                   AggIn, AggOut);
    gemm_combine_kernel<<<gemm_grid, 256, 0, stream>>>(AggIn, AggOut, W3_in, W3_out,
                                                       b3_in, b3_out, act, 0);

    // pool + head
    pool_kernel<<<(N_NODES + 127) / 128, 256, 0, stream>>>(act, batch, pool_sum, cnt);
    head_kernel<<<N_GRAPHS, 64, 0, stream>>>(pool_sum, cnt, ln_w, ln_b, P1w, P1b, P2w, P2b, out);
}